// Round 11
// baseline (599.557 us; speedup 1.0000x reference)
//
#include <hip/hip_runtime.h>
#include <hip/hip_bf16.h>

typedef __hip_bfloat16 bf16;
typedef __attribute__((ext_vector_type(8))) short short8;
typedef __attribute__((ext_vector_type(4))) float floatx4;

__device__ __forceinline__ float b2f(bf16 v) { return __bfloat162float(v); }
__device__ __forceinline__ float us2f(unsigned short u) {
    return __uint_as_float(((unsigned)u) << 16);
}
__device__ __forceinline__ unsigned short f2us(float f) {
    bf16 h = __float2bfloat16(f);
    return *(unsigned short*)&h;
}
__device__ __forceinline__ float lo2f(unsigned hv) { return __uint_as_float(hv << 16); }
__device__ __forceinline__ float hi2f(unsigned hv) { return __uint_as_float(hv & 0xffff0000u); }
__device__ __forceinline__ float leaky(float v) { return v > 0.f ? v : 0.2f * v; }

// flag-aware raw-input read by ELEMENT index: flag==1 -> f32 storage, else bf16
__device__ __forceinline__ float ldw(const void* p, size_t i, int f32) {
    return f32 ? ((const float*)p)[i] : b2f(((const bf16*)p)[i]);
}

// ---------------- dtype detection ----------------
__global__ void k_detect(const void* x, int* flag) {
    int i = blockIdx.x * blockDim.x + threadIdx.x;
    float v = b2f(((const bf16*)x)[i]);
    if (!(fabsf(v) < 1e10f)) atomicOr(flag, 1);  // NaN/inf/huge -> f32 storage
}

// ---------------- fused prep: x->bf16, W transpose->bf16, small weights, node0 ----
__global__ void k_prep_fused(const void* __restrict__ x, unsigned short* __restrict__ Ab,
                             int nx128,
                             const void* __restrict__ gw, unsigned short* __restrict__ Wt,
                             const void* as_, const void* ad_, const void* b_,
                             float* asF, float* adF, float* bF,
                             const int* __restrict__ batch, int* __restrict__ node0, int N,
                             const int* __restrict__ flag, int nbx, int nbN) {
    int b = blockIdx.x;
    int t = threadIdx.x;
    int f32 = *flag;
    if (b < nbx) {
        int i = b * 256 + t;
        if (i < nx128) Ab[i] = f2us(ldw(x, i, f32));
    } else if (b < nbx + 192) {
        int i = (b - nbx) * 256 + t;  // exactly 3*16384
        int l = i >> 14, rem = i & 16383, n = rem >> 7, k = rem & 127;
        Wt[i] = f2us(ldw(gw, (size_t)l * 16384 + (size_t)k * 128 + n, f32));
    } else if (b < nbx + 194) {
        int i = (b - nbx - 192) * 256 + t;
        if (i < 384) {
            asF[i] = ldw(as_, i, f32);
            adF[i] = ldw(ad_, i, f32);
            bF[i] = ldw(b_, i, f32);
        }
    } else {
        int i = (b - nbx - 194) * 256 + t;
        if (i < N) {
            int bb = batch[i];
            if (i == 0 || batch[i - 1] != bb) node0[bb] = i;
        }
    }
}

// ---------------- graph build ----------------
__global__ void k_hist(const int* __restrict__ ei, int* __restrict__ counts,
                       int* __restrict__ rank, int E) {
    int e = blockIdx.x * blockDim.x + threadIdx.x;
    if (e < E) rank[e] = atomicAdd(&counts[ei[E + e]], 1);
}

__global__ void k_scan1(const int* __restrict__ counts, int* __restrict__ offs,
                        int* __restrict__ bsums, int n) {
    __shared__ int s[256];
    int tid = threadIdx.x;
    int i = blockIdx.x * 256 + tid;
    int v = (i < n) ? counts[i] : 0;
    s[tid] = v;
    __syncthreads();
    for (int d = 1; d < 256; d <<= 1) {
        int t = (tid >= d) ? s[tid - d] : 0;
        __syncthreads();
        s[tid] += t;
        __syncthreads();
    }
    int incl = s[tid];
    if (i < n) offs[i] = incl - v;
    if (tid == 255) bsums[blockIdx.x] = incl;
}

__global__ void k_scan2(int* __restrict__ bsums, int nb) {
    __shared__ int s[512];
    int tid = threadIdx.x;
    int v = (tid < nb) ? bsums[tid] : 0;
    s[tid] = v;
    __syncthreads();
    for (int d = 1; d < 512; d <<= 1) {
        int t = (tid >= d) ? s[tid - d] : 0;
        __syncthreads();
        s[tid] += t;
        __syncthreads();
    }
    bsums[tid] = s[tid] - v;
}

__global__ void k_scan3(int* __restrict__ offs, const int* __restrict__ bsums, int n) {
    int i = blockIdx.x * 256 + threadIdx.x;
    if (i < n) offs[i] += bsums[blockIdx.x];
}

// atomic-free scatter
__global__ void k_scatter(const int* __restrict__ ei, const int* __restrict__ offs,
                          const int* __restrict__ rank, int* __restrict__ adj, int E) {
    int e = blockIdx.x * blockDim.x + threadIdx.x;
    if (e < E) {
        int d = ei[E + e];
        adj[offs[d] + rank[e]] = ei[e];
    }
}

// ---------------- degree-sorted node order (counting sort, 64 bins) ----------------
__global__ void k_deghist(const int* __restrict__ counts, int* __restrict__ dhist,
                          int* __restrict__ rankN, int n) {
    __shared__ int lh[64];
    __shared__ int gbase[64];
    int t = threadIdx.x;
    if (t < 64) lh[t] = 0;
    __syncthreads();
    int i = blockIdx.x * 256 + t;
    int d = 0, lr = 0;
    if (i < n) {
        d = min(counts[i], 63);
        lr = atomicAdd(&lh[d], 1);
    }
    __syncthreads();
    if (t < 64 && lh[t] > 0) gbase[t] = atomicAdd(&dhist[t], lh[t]);
    __syncthreads();
    if (i < n) rankN[i] = gbase[d] + lr;
}

__global__ void k_degscan(int* __restrict__ dhist) {
    __shared__ int s[64];
    int t = threadIdx.x;
    int v = dhist[t];
    s[t] = v;
    __syncthreads();
    for (int d = 1; d < 64; d <<= 1) {
        int u = (t >= d) ? s[t - d] : 0;
        __syncthreads();
        s[t] += u;
        __syncthreads();
    }
    dhist[t] = s[t] - v;  // exclusive bin offsets
}

__global__ void k_degscatter(const int* __restrict__ counts, const int* __restrict__ dhist,
                             const int* __restrict__ rankN, int* __restrict__ perm, int n) {
    int i = blockIdx.x * 256 + threadIdx.x;
    if (i < n) {
        int d = min(counts[i], 63);
        perm[dhist[d] + rankN[i]] = i;
    }
}

// ---------------- MFMA GEMM + fused attention scalars ----------------
__global__ __launch_bounds__(256) void k_gemm_mfma(
    const unsigned short* __restrict__ Ab, const unsigned short* __restrict__ Wt,
    unsigned short* __restrict__ Bb, float4* __restrict__ asadv,
    const float* __restrict__ asF, const float* __restrict__ adF, int N) {
    __shared__ unsigned short As[64 * 136];  // staging + C-transpose buffer

    int t = threadIdx.x;
    int r0 = blockIdx.x * 64;

    const short8* Ag = (const short8*)(Ab + (size_t)r0 * 128);
    for (int ch = t; ch < 1024; ch += 256) {
        int row = ch >> 4, c8 = ch & 15;
        *(short8*)&As[row * 136 + c8 * 8] = Ag[ch];
    }
    __syncthreads();

    int lane = t & 63;
    int w = t >> 6;
    int ln = lane & 15;
    int quad = lane >> 4;

    short8 afrag[4];
#pragma unroll
    for (int kt = 0; kt < 4; kt++)
        afrag[kt] = *(const short8*)&As[(w * 16 + ln) * 136 + kt * 32 + quad * 8];
    __syncthreads();

    floatx4 acc[8];
#pragma unroll
    for (int nt = 0; nt < 8; nt++) acc[nt] = (floatx4){0.f, 0.f, 0.f, 0.f};

#pragma unroll
    for (int nt = 0; nt < 8; nt++) {
        const unsigned short* wp = Wt + (size_t)(nt * 16 + ln) * 128 + quad * 8;
#pragma unroll
        for (int kt = 0; kt < 4; kt++) {
            short8 bfrag = *(const short8*)(wp + kt * 32);
            acc[nt] = __builtin_amdgcn_mfma_f32_16x16x32_bf16(afrag[kt], bfrag, acc[nt], 0, 0, 0);
        }
    }

    float as0[4] = {0, 0, 0, 0}, as1[4] = {0, 0, 0, 0};
    float ad0[4] = {0, 0, 0, 0}, ad1[4] = {0, 0, 0, 0};
#pragma unroll
    for (int nt = 0; nt < 8; nt++) {
        float asc = asF[nt * 16 + ln];
        float adc = adF[nt * 16 + ln];
#pragma unroll
        for (int r = 0; r < 4; r++) {
            float v = acc[nt][r];
            As[(w * 16 + quad * 4 + r) * 136 + nt * 16 + ln] = f2us(v);
            if (nt < 4) { as0[r] += v * asc; ad0[r] += v * adc; }
            else        { as1[r] += v * asc; ad1[r] += v * adc; }
        }
    }
#pragma unroll
    for (int mask = 1; mask <= 8; mask <<= 1) {
#pragma unroll
        for (int r = 0; r < 4; r++) {
            as0[r] += __shfl_xor(as0[r], mask);
            as1[r] += __shfl_xor(as1[r], mask);
            ad0[r] += __shfl_xor(ad0[r], mask);
            ad1[r] += __shfl_xor(ad1[r], mask);
        }
    }
    if (ln == 0) {
#pragma unroll
        for (int r = 0; r < 4; r++) {
            int row = r0 + w * 16 + quad * 4 + r;
            asadv[row] = make_float4(as0[r], as1[r], ad0[r], ad1[r]);
        }
    }
    __syncthreads();

    {
        int row = t >> 2;
        int cseg = (t & 3) * 32;
        const short8* srcp = (const short8*)&As[row * 136 + cseg];
        short8* dstp = (short8*)&Bb[(size_t)(r0 + row) * 128 + cseg];
#pragma unroll
        for (int u = 0; u < 4; u++) dstp[u] = srcp[u];
    }
}

// ---------------- GAT aggregation: TWO degree-matched nodes per wave ----------------
// perm (degree-sorted) gives both wave halves the same trip count. Alphas are
// pre-scaled by 1/s; head selection is done by the CONSUMER lane after
// shfl-ing BOTH heads' alphas (R10's source-side preselect read the wrong
// head's alpha — selection must happen after the broadcast).
// Depth-8 pipeline: 16 edges/wave (4 KB) in flight.
__global__ void k_gat_agg(const uint2* __restrict__ Bu2, const float4* __restrict__ asadv,
                          const int* __restrict__ offs, const int* __restrict__ counts,
                          const int* __restrict__ adj, const float* __restrict__ biasF,
                          const int* __restrict__ perm,
                          uint2* __restrict__ Au2, float2* __restrict__ pE,
                          int n, int dorelu) {
    int wave = (blockIdx.x * blockDim.x + threadIdx.x) >> 6;
    int lane = threadIdx.x & 63;
    int hl = lane & 31;          // lane within node-half
    int hb = lane & 32;          // shfl broadcast base for this half
    int pidx = wave * 2 + (lane >> 5);
    if (pidx >= n) return;
    int node = perm[pidx];
    int head = hl >> 4;          // channels 4hl..4hl+3

    float4 self = asadv[node];
    float ad0 = self.z, ad1 = self.w;
    float es0 = __expf(leaky(self.x + ad0));
    float es1 = __expf(leaky(self.y + ad1));

    int o = offs[node], c = counts[node];
    uint2 hvs = Bu2[(size_t)node * 32 + hl];
    float acc0, acc1, acc2, acc3;

    if (c <= 32) {
        // ---- fast path ----
        int src_r = 0;
        float p0 = 0.f, p1 = 0.f;
        if (hl < c) {
            src_r = adj[o + hl];
            float4 av = asadv[src_r];
            p0 = __expf(leaky(av.x + ad0));
            p1 = __expf(leaky(av.y + ad1));
        }
        float t0 = p0, t1 = p1;
#pragma unroll
        for (int mask = 1; mask <= 16; mask <<= 1) {
            t0 += __shfl_xor(t0, mask);
            t1 += __shfl_xor(t1, mask);
        }
        float inv0 = 1.f / (es0 + t0 + 1e-16f);
        float inv1 = 1.f / (es1 + t1 + 1e-16f);
        p0 *= inv0;                       // pre-scaled alphas (both heads kept)
        p1 *= inv1;
        float aself = head ? es1 * inv1 : es0 * inv0;
        acc0 = aself * lo2f(hvs.x);
        acc1 = aself * hi2f(hvs.x);
        acc2 = aself * lo2f(hvs.y);
        acc3 = aself * hi2f(hvs.y);

        // prologue: prefetch rows for edges 0..7
        uint2 hq[8];
#pragma unroll
        for (int j = 0; j < 8; j++) {
            int s2 = __shfl(src_r, hb + j);
            hq[j] = make_uint2(0u, 0u);
            if (j < c) hq[j] = Bu2[(size_t)s2 * 32 + hl];
        }

        for (int base = 0; base < c; base += 8) {
            uint2 cur[8];
            float av8[8];
#pragma unroll
            for (int j = 0; j < 8; j++) {
                cur[j] = hq[j];
                int idx = (base + j) & 31;
                float a0 = __shfl(p0, hb + idx);   // both heads broadcast;
                float a1 = __shfl(p1, hb + idx);   // consumer selects its head
                float a = head ? a1 : a0;
                av8[j] = (base + j < c) ? a : 0.f; // tail guard (stale cur is finite)
            }
            // issue next 8 loads before consuming cur
#pragma unroll
            for (int j = 0; j < 8; j++) {
                int nx = base + 8 + j;
                int s2 = __shfl(src_r, hb + (nx & 31));
                if (nx < c) hq[j] = Bu2[(size_t)s2 * 32 + hl];
            }
#pragma unroll
            for (int j = 0; j < 8; j++) {
                acc0 += av8[j] * lo2f(cur[j].x);
                acc1 += av8[j] * hi2f(cur[j].x);
                acc2 += av8[j] * lo2f(cur[j].y);
                acc3 += av8[j] * hi2f(cur[j].y);
            }
        }
    } else {
        // ---- slow path (rare, c>32): alphas staged in global scratch ----
        float sum0 = es0, sum1 = es1;
        for (int base = 0; base < c; base += 32) {
            int i = base + hl;
            float p0 = 0.f, p1 = 0.f;
            if (i < c) {
                int s = adj[o + i];
                float4 av = asadv[s];
                p0 = __expf(leaky(av.x + ad0));
                p1 = __expf(leaky(av.y + ad1));
                pE[o + i] = make_float2(p0, p1);
            }
            float t0 = p0, t1 = p1;
#pragma unroll
            for (int mask = 1; mask <= 16; mask <<= 1) {
                t0 += __shfl_xor(t0, mask);
                t1 += __shfl_xor(t1, mask);
            }
            sum0 += t0; sum1 += t1;
        }
        float inv0 = 1.f / (sum0 + 1e-16f);
        float inv1 = 1.f / (sum1 + 1e-16f);
        float aself = head ? es1 * inv1 : es0 * inv0;
        float invh = head ? inv1 : inv0;
        acc0 = aself * lo2f(hvs.x);
        acc1 = aself * hi2f(hvs.x);
        acc2 = aself * lo2f(hvs.y);
        acc3 = aself * hi2f(hvs.y);
        for (int i = 0; i < c; i++) {
            int s = adj[o + i];
            float2 pp = pE[o + i];
            uint2 hv = Bu2[(size_t)s * 32 + hl];
            float a = (head ? pp.y : pp.x) * invh;
            acc0 += a * lo2f(hv.x);
            acc1 += a * hi2f(hv.x);
            acc2 += a * lo2f(hv.y);
            acc3 += a * hi2f(hv.y);
        }
    }

    float4 bb = ((const float4*)biasF)[hl];
    float o0 = acc0 + bb.x;
    float o1 = acc1 + bb.y;
    float o2 = acc2 + bb.z;
    float o3 = acc3 + bb.w;
    if (dorelu) {
        o0 = fmaxf(o0, 0.f); o1 = fmaxf(o1, 0.f);
        o2 = fmaxf(o2, 0.f); o3 = fmaxf(o3, 0.f);
    }
    Au2[(size_t)node * 32 + hl] =
        make_uint2(((unsigned)f2us(o1) << 16) | f2us(o0),
                   ((unsigned)f2us(o3) << 16) | f2us(o2));
}

// ---------------- heads: one block (4 waves) per graph ----------------
__global__ __launch_bounds__(256) void k_heads(
    const unsigned short* __restrict__ Ab, const void* __restrict__ x,
    const int* __restrict__ node0,
    const void* sW, const void* sb,
    const void* pW1, const void* pb1, const void* pW2, const void* pb2,
    const void* cW1, const void* cb1, const void* cW2, const void* cb2,
    const void* fW1, const void* fb1, const void* fW2, const void* fb2,
    const void* bW1, const void* bb1, const void* bW2, const void* bb2,
    const void* zW1, const void* zb1, const void* zW2, const void* zb2,
    void* __restrict__ outv, const int* __restrict__ flag) {
    int g = blockIdx.x;
    int t = threadIdx.x;
    int w = t >> 6;
    int lane = t & 63;
    int f32 = *flag;
    bf16* outb = (bf16*)outv;
    float* outf = (float*)outv;
    __shared__ float in150[152];
    __shared__ float part[4][64];
    __shared__ float zf[64];
    __shared__ float tmp[64];
    __shared__ float bin[96];

#define STORE_OUT(idx, val) do { if (f32) outf[idx] = (val); else outb[idx] = __float2bfloat16(val); } while (0)

    int n0 = node0[g];
    if (t < 128) in150[t] = us2f(Ab[(size_t)n0 * 128 + t]);
    else if (t < 150) in150[t] = ldw(x, (size_t)n0 * 128 + (t - 128), f32);
    __syncthreads();
    if (t >= 64 && t < 86) bin[t] = in150[128 + (t - 64)];

    {
        int i0 = w * 38, i1 = min(150, i0 + 38);
        float p = 0.f;
        for (int i = i0; i < i1; i++) p += in150[i] * ldw(sW, (size_t)i * 64 + lane, f32);
        part[w][lane] = p;
    }
    __syncthreads();
    if (w == 0) {
        float a = part[0][lane] + part[1][lane] + part[2][lane] + part[3][lane]
                + ldw(sb, lane, f32);
        a = fmaxf(a, 0.f);
        zf[lane] = a;
        bin[lane] = a;
    }
    __syncthreads();

    for (int k = 0; k < 3; k++) {
        {
            int i0 = w * 16;
            float p = 0.f;
            for (int i = i0; i < i0 + 16; i++)
                p += zf[i] * ldw(pW1, (size_t)k * 4096 + (size_t)i * 64 + lane, f32);
            part[w][lane] = p;
        }
        __syncthreads();
        if (w == 0) {
            float a = part[0][lane] + part[1][lane] + part[2][lane] + part[3][lane]
                    + ldw(pb1, k * 64 + lane, f32);
            tmp[lane] = fmaxf(a, 0.f);
        }
        __syncthreads();
        if (w < 3) {
            float v = tmp[lane] * ldw(pW2, (size_t)k * 192 + (size_t)lane * 3 + w, f32);
#pragma unroll
            for (int mask = 1; mask <= 32; mask <<= 1) v += __shfl_xor(v, mask);
            if (lane == 0) STORE_OUT(k * 768 + g * 3 + w, v + ldw(pb2, k * 3 + w, f32));
        }
        __syncthreads();
    }

    {
        int i0 = w * 16;
        float p = 0.f;
        for (int i = i0; i < i0 + 16; i++)
            p += zf[i] * ldw(cW1, (size_t)i * 64 + lane, f32);
        part[w][lane] = p;
    }
    __syncthreads();
    if (w == 0) {
        float a = part[0][lane] + part[1][lane] + part[2][lane] + part[3][lane]
                + ldw(cb1, lane, f32);
        tmp[lane] = fmaxf(a, 0.f);
    }
    __syncthreads();
    for (int base = 0; base < 5; base += 4) {
        int o = base + w;
        if (o < 5) {
            float v = tmp[lane] * ldw(cW2, (size_t)lane * 5 + o, f32);
#pragma unroll
            for (int mask = 1; mask <= 32; mask <<= 1) v += __shfl_xor(v, mask);
            if (lane == 0) {
                float r = v + ldw(cb2, o, f32);
                bin[86 + o] = r;
                STORE_OUT(2304 + g * 5 + o, r);
            }
        }
        __syncthreads();
    }

    for (int k = 0; k < 2; k++) {
        {
            int i0 = w * 16;
            float p = 0.f;
            for (int i = i0; i < i0 + 16; i++)
                p += zf[i] * ldw(fW1, (size_t)k * 4096 + (size_t)i * 64 + lane, f32);
            part[w][lane] = p;
        }
        __syncthreads();
        if (w == 0) {
            float a = part[0][lane] + part[1][lane] + part[2][lane] + part[3][lane]
                    + ldw(fb1, k * 64 + lane, f32);
            tmp[lane] = fmaxf(a, 0.f);
        }
        __syncthreads();
        if (w == 0) {
            float v = tmp[lane] * ldw(fW2, k * 64 + lane, f32);
#pragma unroll
            for (int mask = 1; mask <= 32; mask <<= 1) v += __shfl_xor(v, mask);
            if (lane == 0) {
                float r = v + ldw(fb2, k, f32);
                bin[91 + k] = r;
                STORE_OUT(3584 + k * 256 + g, r);
            }
        }
        __syncthreads();
    }

    {
        int i0 = w * 24, i1 = min(93, i0 + 24);
        float p = 0.f;
        for (int i = i0; i < i1; i++) p += bin[i] * ldw(bW1, (size_t)i * 64 + lane, f32);
        part[w][lane] = p;
    }
    __syncthreads();
    if (w == 0) {
        float a = part[0][lane] + part[1][lane] + part[2][lane] + part[3][lane]
                + ldw(bb1, lane, f32);
        tmp[lane] = fmaxf(a, 0.f);
    }
    __syncthreads();
    if (w == 0) {
        float v = tmp[lane] * ldw(bW2, lane, f32);
#pragma unroll
        for (int mask = 1; mask <= 32; mask <<= 1) v += __shfl_xor(v, mask);
        if (lane == 0) {
            float r = v + ldw(bb2, 0, f32);
            bin[93] = r;
            STORE_OUT(4096 + g, r);
        }
    }
    __syncthreads();

    {
        int i0 = w * 24, i1 = min(94, i0 + 24);
        float p = 0.f;
        for (int i = i0; i < i1; i++) p += bin[i] * ldw(zW1, (size_t)i * 64 + lane, f32);
        part[w][lane] = p;
    }
    __syncthreads();
    if (w == 0) {
        float a = part[0][lane] + part[1][lane] + part[2][lane] + part[3][lane]
                + ldw(zb1, lane, f32);
        tmp[lane] = fmaxf(a, 0.f);
    }
    __syncthreads();
    for (int base = 0; base < 8; base += 4) {
        int o = base + w;
        float v = tmp[lane] * ldw(zW2, (size_t)lane * 8 + o, f32);
#pragma unroll
        for (int mask = 1; mask <= 32; mask <<= 1) v += __shfl_xor(v, mask);
        if (lane == 0) STORE_OUT(4352 + g * 8 + o, v + ldw(zb2, o, f32));
    }
#undef STORE_OUT
}

// ---------------- host ----------------

extern "C" void kernel_launch(void* const* d_in, const int* in_sizes, int n_in,
                              void* d_out, int out_size, void* d_ws, size_t ws_size,
                              hipStream_t stream) {
    const void* x     = d_in[0];
    const int*  ei    = (const int*)d_in[1];
    const int*  batch = (const int*)d_in[2];

    int N = in_sizes[0] / 128;
    int E = in_sizes[1] / 2;

    char* w = (char*)d_ws;
    float4* asad = (float4*)w;              w += (size_t)N * 16;
    unsigned short* A = (unsigned short*)w; w += (size_t)N * 128 * 2;
    unsigned short* B = (unsigned short*)w; w += (size_t)N * 128 * 2;
    float2* pE = (float2*)w;                w += (size_t)E * 8;
    unsigned short* Wt = (unsigned short*)w; w += 3 * 16384 * 2;
    float* asF = (float*)w;                 w += 384 * 4;
    float* adF = (float*)w;                 w += 384 * 4;
    float* bF = (float*)w;                  w += 384 * 4;
    int* counts = (int*)w;                  w += (size_t)N * 4;
    int* offs = (int*)w;                    w += (size_t)N * 4;
    int* rank = (int*)w;                    w += (size_t)E * 4;
    int* adj = (int*)w;                     w += (size_t)E * 4;
    int* rankN = (int*)w;                   w += (size_t)N * 4;
    int* perm = (int*)w;                    w += (size_t)N * 4;
    int* bsums = (int*)w;                   w += 512 * 4;
    int* node0 = (int*)w;                   w += 256 * 4;
    int* dhist = (int*)w;                   w += 64 * 4;
    int* flag = (int*)w;                    w += 64;

    int nb = (N + 255) / 256;
    int nbx = (N * 128 + 255) / 256;

    hipMemsetAsync(flag, 0, 64, stream);
    hipMemsetAsync(counts, 0, (size_t)N * 4, stream);
    hipMemsetAsync(dhist, 0, 64 * 4, stream);

    k_detect<<<16, 256, 0, stream>>>(x, flag);

    k_prep_fused<<<nbx + 194 + nb, 256, 0, stream>>>(
        x, A, N * 128, d_in[3], Wt, d_in[4], d_in[5], d_in[6],
        asF, adF, bF, batch, node0, N, flag, nbx, nb);

    k_hist<<<(E + 255) / 256, 256, 0, stream>>>(ei, counts, rank, E);
    k_scan1<<<nb, 256, 0, stream>>>(counts, offs, bsums, N);
    k_scan2<<<1, 512, 0, stream>>>(bsums, nb);
    k_scan3<<<nb, 256, 0, stream>>>(offs, bsums, N);
    k_scatter<<<(E + 255) / 256, 256, 0, stream>>>(ei, offs, rank, adj, E);

    // degree-sorted node processing order
    k_deghist<<<nb, 256, 0, stream>>>(counts, dhist, rankN, N);
    k_degscan<<<1, 64, 0, stream>>>(dhist);
    k_degscatter<<<nb, 256, 0, stream>>>(counts, dhist, rankN, perm, N);

    // agg grid: 2 nodes per wave, 4 waves per block
    int nwaves = (N + 1) / 2;
    int aggblocks = (nwaves + 3) / 4;
    for (int l = 0; l < 3; l++) {
        k_gemm_mfma<<<(N + 63) / 64, 256, 0, stream>>>(
            A, Wt + (size_t)l * 16384, B, asad, asF + l * 128, adF + l * 128, N);
        k_gat_agg<<<aggblocks, 256, 0, stream>>>(
            (const uint2*)B, asad, offs, counts, adj,
            bF + l * 128, perm, (uint2*)A, pE, N, (l < 2) ? 1 : 0);
    }

    k_heads<<<256, 256, 0, stream>>>(A, x, node0,
                                     d_in[7], d_in[8], d_in[9], d_in[10], d_in[11], d_in[12],
                                     d_in[13], d_in[14], d_in[15], d_in[16],
                                     d_in[17], d_in[18], d_in[19], d_in[20],
                                     d_in[21], d_in[22], d_in[23], d_in[24],
                                     d_in[25], d_in[26], d_in[27], d_in[28],
                                     d_out, flag);
}

// Round 12
// 581.865 us; speedup vs baseline: 1.0304x; 1.0304x over previous
//
#include <hip/hip_runtime.h>
#include <hip/hip_bf16.h>

typedef __hip_bfloat16 bf16;
typedef __attribute__((ext_vector_type(8))) short short8;
typedef __attribute__((ext_vector_type(4))) float floatx4;

__device__ __forceinline__ float b2f(bf16 v) { return __bfloat162float(v); }
__device__ __forceinline__ float us2f(unsigned short u) {
    return __uint_as_float(((unsigned)u) << 16);
}
__device__ __forceinline__ unsigned short f2us(float f) {
    bf16 h = __float2bfloat16(f);
    return *(unsigned short*)&h;
}
__device__ __forceinline__ float lo2f(unsigned hv) { return __uint_as_float(hv << 16); }
__device__ __forceinline__ float hi2f(unsigned hv) { return __uint_as_float(hv & 0xffff0000u); }
__device__ __forceinline__ float leaky(float v) { return v > 0.f ? v : 0.2f * v; }

// flag-aware raw-input read by ELEMENT index: flag==1 -> f32 storage, else bf16
__device__ __forceinline__ float ldw(const void* p, size_t i, int f32) {
    return f32 ? ((const float*)p)[i] : b2f(((const bf16*)p)[i]);
}

// ---------------- dtype detection ----------------
__global__ void k_detect(const void* x, int* flag) {
    int i = blockIdx.x * blockDim.x + threadIdx.x;
    float v = b2f(((const bf16*)x)[i]);
    if (!(fabsf(v) < 1e10f)) atomicOr(flag, 1);  // NaN/inf/huge -> f32 storage
}

// ---------------- fused prep: x->bf16, W transpose->bf16, small weights, node0 ----
__global__ void k_prep_fused(const void* __restrict__ x, unsigned short* __restrict__ Ab,
                             int nx128,
                             const void* __restrict__ gw, unsigned short* __restrict__ Wt,
                             const void* as_, const void* ad_, const void* b_,
                             float* asF, float* adF, float* bF,
                             const int* __restrict__ batch, int* __restrict__ node0, int N,
                             const int* __restrict__ flag, int nbx, int nbN) {
    int b = blockIdx.x;
    int t = threadIdx.x;
    int f32 = *flag;
    if (b < nbx) {
        int i = b * 256 + t;
        if (i < nx128) Ab[i] = f2us(ldw(x, i, f32));
    } else if (b < nbx + 192) {
        int i = (b - nbx) * 256 + t;  // exactly 3*16384
        int l = i >> 14, rem = i & 16383, n = rem >> 7, k = rem & 127;
        Wt[i] = f2us(ldw(gw, (size_t)l * 16384 + (size_t)k * 128 + n, f32));
    } else if (b < nbx + 194) {
        int i = (b - nbx - 192) * 256 + t;
        if (i < 384) {
            asF[i] = ldw(as_, i, f32);
            adF[i] = ldw(ad_, i, f32);
            bF[i] = ldw(b_, i, f32);
        }
    } else {
        int i = (b - nbx - 194) * 256 + t;
        if (i < N) {
            int bb = batch[i];
            if (i == 0 || batch[i - 1] != bb) node0[bb] = i;
        }
    }
}

// ---------------- graph build ----------------
__global__ void k_hist(const int* __restrict__ ei, int* __restrict__ counts,
                       int* __restrict__ rank, int E) {
    int e = blockIdx.x * blockDim.x + threadIdx.x;
    if (e < E) rank[e] = atomicAdd(&counts[ei[E + e]], 1);
}

__global__ void k_scan1(const int* __restrict__ counts, int* __restrict__ offs,
                        int* __restrict__ bsums, int n) {
    __shared__ int s[256];
    int tid = threadIdx.x;
    int i = blockIdx.x * 256 + tid;
    int v = (i < n) ? counts[i] : 0;
    s[tid] = v;
    __syncthreads();
    for (int d = 1; d < 256; d <<= 1) {
        int t = (tid >= d) ? s[tid - d] : 0;
        __syncthreads();
        s[tid] += t;
        __syncthreads();
    }
    int incl = s[tid];
    if (i < n) offs[i] = incl - v;
    if (tid == 255) bsums[blockIdx.x] = incl;
}

__global__ void k_scan2(int* __restrict__ bsums, int nb) {
    __shared__ int s[512];
    int tid = threadIdx.x;
    int v = (tid < nb) ? bsums[tid] : 0;
    s[tid] = v;
    __syncthreads();
    for (int d = 1; d < 512; d <<= 1) {
        int t = (tid >= d) ? s[tid - d] : 0;
        __syncthreads();
        s[tid] += t;
        __syncthreads();
    }
    bsums[tid] = s[tid] - v;
}

__global__ void k_scan3(int* __restrict__ offs, const int* __restrict__ bsums, int n) {
    int i = blockIdx.x * 256 + threadIdx.x;
    if (i < n) offs[i] += bsums[blockIdx.x];
}

// atomic-free scatter
__global__ void k_scatter(const int* __restrict__ ei, const int* __restrict__ offs,
                          const int* __restrict__ rank, int* __restrict__ adj, int E) {
    int e = blockIdx.x * blockDim.x + threadIdx.x;
    if (e < E) {
        int d = ei[E + e];
        adj[offs[d] + rank[e]] = ei[e];
    }
}

// ---------------- MFMA GEMM + fused attention scalars ----------------
// A-fragments load DIRECTLY from global (16 B/lane, 64 B-line coalesced) —
// LDS used only for the C-transpose epilogue buffer.
__global__ __launch_bounds__(256) void k_gemm_mfma(
    const unsigned short* __restrict__ Ab, const unsigned short* __restrict__ Wt,
    unsigned short* __restrict__ Bb, float4* __restrict__ asadv,
    const float* __restrict__ asF, const float* __restrict__ adF, int N) {
    __shared__ unsigned short Cs[64 * 136];

    int t = threadIdx.x;
    int r0 = blockIdx.x * 64;

    int lane = t & 63;
    int w = t >> 6;
    int ln = lane & 15;
    int quad = lane >> 4;

    int arow = r0 + w * 16 + ln;
    if (arow >= N) arow = N - 1;  // clamp (stores are guarded)
    const unsigned short* ap = Ab + (size_t)arow * 128 + quad * 8;

    short8 afrag[4];
#pragma unroll
    for (int kt = 0; kt < 4; kt++)
        afrag[kt] = *(const short8*)(ap + kt * 32);

    floatx4 acc[8];
#pragma unroll
    for (int nt = 0; nt < 8; nt++) acc[nt] = (floatx4){0.f, 0.f, 0.f, 0.f};

#pragma unroll
    for (int nt = 0; nt < 8; nt++) {
        const unsigned short* wp = Wt + (size_t)(nt * 16 + ln) * 128 + quad * 8;
#pragma unroll
        for (int kt = 0; kt < 4; kt++) {
            short8 bfrag = *(const short8*)(wp + kt * 32);
            acc[nt] = __builtin_amdgcn_mfma_f32_16x16x32_bf16(afrag[kt], bfrag, acc[nt], 0, 0, 0);
        }
    }

    float as0[4] = {0, 0, 0, 0}, as1[4] = {0, 0, 0, 0};
    float ad0[4] = {0, 0, 0, 0}, ad1[4] = {0, 0, 0, 0};
#pragma unroll
    for (int nt = 0; nt < 8; nt++) {
        float asc = asF[nt * 16 + ln];
        float adc = adF[nt * 16 + ln];
#pragma unroll
        for (int r = 0; r < 4; r++) {
            float v = acc[nt][r];
            Cs[(w * 16 + quad * 4 + r) * 136 + nt * 16 + ln] = f2us(v);
            if (nt < 4) { as0[r] += v * asc; ad0[r] += v * adc; }
            else        { as1[r] += v * asc; ad1[r] += v * adc; }
        }
    }
#pragma unroll
    for (int mask = 1; mask <= 8; mask <<= 1) {
#pragma unroll
        for (int r = 0; r < 4; r++) {
            as0[r] += __shfl_xor(as0[r], mask);
            as1[r] += __shfl_xor(as1[r], mask);
            ad0[r] += __shfl_xor(ad0[r], mask);
            ad1[r] += __shfl_xor(ad1[r], mask);
        }
    }
    if (ln == 0) {
#pragma unroll
        for (int r = 0; r < 4; r++) {
            int row = r0 + w * 16 + quad * 4 + r;
            if (row < N) asadv[row] = make_float4(as0[r], as1[r], ad0[r], ad1[r]);
        }
    }
    __syncthreads();

    {
        int row = t >> 2;
        int cseg = (t & 3) * 32;
        if (r0 + row < N) {
            const short8* srcp = (const short8*)&Cs[row * 136 + cseg];
            short8* dstp = (short8*)&Bb[(size_t)(r0 + row) * 128 + cseg];
#pragma unroll
            for (int u = 0; u < 4; u++) dstp[u] = srcp[u];
        }
    }
}

// ---------------- GAT aggregation: 2 nodes/wave, even/odd edge split ----------------
// Each node's 32 lanes split: sub=0 (lanes 0-15) even edges, sub=1 odd edges.
// Lane covers 8 channels (one uint4 = 16 B row segment). Partial sums combine
// via shfl_xor(16); sub 0 seeds the self term. ~half the VALU insts/edge of
// the uint2 variant. Alphas: both heads shfl'd, consumer selects (R10 lesson).
__global__ void k_gat_agg(const uint4* __restrict__ Bu4, const float4* __restrict__ asadv,
                          const int* __restrict__ offs, const int* __restrict__ counts,
                          const int* __restrict__ adj, const float* __restrict__ biasF,
                          uint4* __restrict__ Au4, float2* __restrict__ pE,
                          int n, int dorelu) {
    int wave = (blockIdx.x * blockDim.x + threadIdx.x) >> 6;
    int lane = threadIdx.x & 63;
    int hl = lane & 31;          // lane within node-half
    int hb = lane & 32;          // shfl broadcast base for this half
    int node = wave * 2 + (lane >> 5);
    if (node >= n) return;
    int sub = hl >> 4;           // 0: even edges, 1: odd edges
    int sl = hl & 15;            // channels 8*sl .. 8*sl+7
    int head = sl >> 3;          // uniform per lane

    float4 self = asadv[node];
    float ad0 = self.z, ad1 = self.w;
    float es0 = __expf(leaky(self.x + ad0));
    float es1 = __expf(leaky(self.y + ad1));

    int o = offs[node], c = counts[node];
    uint4 hvs = Bu4[(size_t)node * 16 + sl];
    float acc[8];

    if (c <= 32) {
        // ---- fast path: alphas in registers (32 lanes of the half) ----
        int src_r = 0;
        float p0 = 0.f, p1 = 0.f;
        if (hl < c) {
            src_r = adj[o + hl];
            float4 av = asadv[src_r];
            p0 = __expf(leaky(av.x + ad0));
            p1 = __expf(leaky(av.y + ad1));
        }
        float t0 = p0, t1 = p1;
#pragma unroll
        for (int mask = 1; mask <= 16; mask <<= 1) {
            t0 += __shfl_xor(t0, mask);
            t1 += __shfl_xor(t1, mask);
        }
        float inv0 = 1.f / (es0 + t0 + 1e-16f);
        float inv1 = 1.f / (es1 + t1 + 1e-16f);
        p0 *= inv0;
        p1 *= inv1;
        float aself = (head ? es1 * inv1 : es0 * inv0) * (sub == 0 ? 1.f : 0.f);
        acc[0] = aself * lo2f(hvs.x); acc[1] = aself * hi2f(hvs.x);
        acc[2] = aself * lo2f(hvs.y); acc[3] = aself * hi2f(hvs.y);
        acc[4] = aself * lo2f(hvs.z); acc[5] = aself * hi2f(hvs.z);
        acc[6] = aself * lo2f(hvs.w); acc[7] = aself * hi2f(hvs.w);

        int imax = (c + 1) >> 1;   // per-sub trip count (max over subs)
        // prologue: prefetch iters 0..3 (this sub's edges 2j+sub)
        uint4 hq[4];
#pragma unroll
        for (int j = 0; j < 4; j++) {
            int e = 2 * j + sub;
            int s2 = __shfl(src_r, hb + (e & 31));
            hq[j] = make_uint4(0u, 0u, 0u, 0u);
            if (e < c) hq[j] = Bu4[(size_t)s2 * 16 + sl];
        }

        for (int base = 0; base < imax; base += 4) {
            uint4 cur[4];
            float av4[4];
#pragma unroll
            for (int j = 0; j < 4; j++) {
                cur[j] = hq[j];
                int e = 2 * (base + j) + sub;
                float a0 = __shfl(p0, hb + (e & 31));
                float a1 = __shfl(p1, hb + (e & 31));
                float a = head ? a1 : a0;
                av4[j] = (e < c) ? a : 0.f;   // tail guard (stale cur is finite)
            }
            // issue next 4 loads before consuming cur
#pragma unroll
            for (int j = 0; j < 4; j++) {
                int e = 2 * (base + 4 + j) + sub;
                int s2 = __shfl(src_r, hb + (e & 31));
                if (e < c) hq[j] = Bu4[(size_t)s2 * 16 + sl];
            }
#pragma unroll
            for (int j = 0; j < 4; j++) {
                acc[0] += av4[j] * lo2f(cur[j].x); acc[1] += av4[j] * hi2f(cur[j].x);
                acc[2] += av4[j] * lo2f(cur[j].y); acc[3] += av4[j] * hi2f(cur[j].y);
                acc[4] += av4[j] * lo2f(cur[j].z); acc[5] += av4[j] * hi2f(cur[j].z);
                acc[6] += av4[j] * lo2f(cur[j].w); acc[7] += av4[j] * hi2f(cur[j].w);
            }
        }
    } else {
        // ---- slow path (rare, c>32): alphas staged in global scratch ----
        float sum0 = es0, sum1 = es1;
        for (int base = 0; base < c; base += 32) {
            int i = base + hl;
            float p0 = 0.f, p1 = 0.f;
            if (i < c) {
                int s = adj[o + i];
                float4 av = asadv[s];
                p0 = __expf(leaky(av.x + ad0));
                p1 = __expf(leaky(av.y + ad1));
                pE[o + i] = make_float2(p0, p1);
            }
            float t0 = p0, t1 = p1;
#pragma unroll
            for (int mask = 1; mask <= 16; mask <<= 1) {
                t0 += __shfl_xor(t0, mask);
                t1 += __shfl_xor(t1, mask);
            }
            sum0 += t0; sum1 += t1;
        }
        float inv0 = 1.f / (sum0 + 1e-16f);
        float inv1 = 1.f / (sum1 + 1e-16f);
        float invh = head ? inv1 : inv0;
        float aself = (head ? es1 * inv1 : es0 * inv0) * (sub == 0 ? 1.f : 0.f);
        acc[0] = aself * lo2f(hvs.x); acc[1] = aself * hi2f(hvs.x);
        acc[2] = aself * lo2f(hvs.y); acc[3] = aself * hi2f(hvs.y);
        acc[4] = aself * lo2f(hvs.z); acc[5] = aself * hi2f(hvs.z);
        acc[6] = aself * lo2f(hvs.w); acc[7] = aself * hi2f(hvs.w);
        for (int i = sub; i < c; i += 2) {
            int s = adj[o + i];
            float2 pp = pE[o + i];
            uint4 hv = Bu4[(size_t)s * 16 + sl];
            float a = (head ? pp.y : pp.x) * invh;
            acc[0] += a * lo2f(hv.x); acc[1] += a * hi2f(hv.x);
            acc[2] += a * lo2f(hv.y); acc[3] += a * hi2f(hv.y);
            acc[4] += a * lo2f(hv.z); acc[5] += a * hi2f(hv.z);
            acc[6] += a * lo2f(hv.w); acc[7] += a * hi2f(hv.w);
        }
    }

    // combine even/odd partial sums
#pragma unroll
    for (int k = 0; k < 8; k++) acc[k] += __shfl_xor(acc[k], 16);

    if (sub == 0) {
        float4 bb0 = ((const float4*)biasF)[2 * sl];
        float4 bb1 = ((const float4*)biasF)[2 * sl + 1];
        float o0 = acc[0] + bb0.x, o1 = acc[1] + bb0.y;
        float o2 = acc[2] + bb0.z, o3 = acc[3] + bb0.w;
        float o4 = acc[4] + bb1.x, o5 = acc[5] + bb1.y;
        float o6 = acc[6] + bb1.z, o7 = acc[7] + bb1.w;
        if (dorelu) {
            o0 = fmaxf(o0, 0.f); o1 = fmaxf(o1, 0.f);
            o2 = fmaxf(o2, 0.f); o3 = fmaxf(o3, 0.f);
            o4 = fmaxf(o4, 0.f); o5 = fmaxf(o5, 0.f);
            o6 = fmaxf(o6, 0.f); o7 = fmaxf(o7, 0.f);
        }
        Au4[(size_t)node * 16 + sl] = make_uint4(
            ((unsigned)f2us(o1) << 16) | f2us(o0),
            ((unsigned)f2us(o3) << 16) | f2us(o2),
            ((unsigned)f2us(o5) << 16) | f2us(o4),
            ((unsigned)f2us(o7) << 16) | f2us(o6));
    }
}

// ---------------- heads: one block (4 waves) per graph ----------------
__global__ __launch_bounds__(256) void k_heads(
    const unsigned short* __restrict__ Ab, const void* __restrict__ x,
    const int* __restrict__ node0,
    const void* sW, const void* sb,
    const void* pW1, const void* pb1, const void* pW2, const void* pb2,
    const void* cW1, const void* cb1, const void* cW2, const void* cb2,
    const void* fW1, const void* fb1, const void* fW2, const void* fb2,
    const void* bW1, const void* bb1, const void* bW2, const void* bb2,
    const void* zW1, const void* zb1, const void* zW2, const void* zb2,
    void* __restrict__ outv, const int* __restrict__ flag) {
    int g = blockIdx.x;
    int t = threadIdx.x;
    int w = t >> 6;
    int lane = t & 63;
    int f32 = *flag;
    bf16* outb = (bf16*)outv;
    float* outf = (float*)outv;
    __shared__ float in150[152];
    __shared__ float part[4][64];
    __shared__ float zf[64];
    __shared__ float tmp[64];
    __shared__ float bin[96];

#define STORE_OUT(idx, val) do { if (f32) outf[idx] = (val); else outb[idx] = __float2bfloat16(val); } while (0)

    int n0 = node0[g];
    if (t < 128) in150[t] = us2f(Ab[(size_t)n0 * 128 + t]);
    else if (t < 150) in150[t] = ldw(x, (size_t)n0 * 128 + (t - 128), f32);
    __syncthreads();
    if (t >= 64 && t < 86) bin[t] = in150[128 + (t - 64)];

    {
        int i0 = w * 38, i1 = min(150, i0 + 38);
        float p = 0.f;
        for (int i = i0; i < i1; i++) p += in150[i] * ldw(sW, (size_t)i * 64 + lane, f32);
        part[w][lane] = p;
    }
    __syncthreads();
    if (w == 0) {
        float a = part[0][lane] + part[1][lane] + part[2][lane] + part[3][lane]
                + ldw(sb, lane, f32);
        a = fmaxf(a, 0.f);
        zf[lane] = a;
        bin[lane] = a;
    }
    __syncthreads();

    for (int k = 0; k < 3; k++) {
        {
            int i0 = w * 16;
            float p = 0.f;
            for (int i = i0; i < i0 + 16; i++)
                p += zf[i] * ldw(pW1, (size_t)k * 4096 + (size_t)i * 64 + lane, f32);
            part[w][lane] = p;
        }
        __syncthreads();
        if (w == 0) {
            float a = part[0][lane] + part[1][lane] + part[2][lane] + part[3][lane]
                    + ldw(pb1, k * 64 + lane, f32);
            tmp[lane] = fmaxf(a, 0.f);
        }
        __syncthreads();
        if (w < 3) {
            float v = tmp[lane] * ldw(pW2, (size_t)k * 192 + (size_t)lane * 3 + w, f32);
#pragma unroll
            for (int mask = 1; mask <= 32; mask <<= 1) v += __shfl_xor(v, mask);
            if (lane == 0) STORE_OUT(k * 768 + g * 3 + w, v + ldw(pb2, k * 3 + w, f32));
        }
        __syncthreads();
    }

    {
        int i0 = w * 16;
        float p = 0.f;
        for (int i = i0; i < i0 + 16; i++)
            p += zf[i] * ldw(cW1, (size_t)i * 64 + lane, f32);
        part[w][lane] = p;
    }
    __syncthreads();
    if (w == 0) {
        float a = part[0][lane] + part[1][lane] + part[2][lane] + part[3][lane]
                + ldw(cb1, lane, f32);
        tmp[lane] = fmaxf(a, 0.f);
    }
    __syncthreads();
    for (int base = 0; base < 5; base += 4) {
        int o = base + w;
        if (o < 5) {
            float v = tmp[lane] * ldw(cW2, (size_t)lane * 5 + o, f32);
#pragma unroll
            for (int mask = 1; mask <= 32; mask <<= 1) v += __shfl_xor(v, mask);
            if (lane == 0) {
                float r = v + ldw(cb2, o, f32);
                bin[86 + o] = r;
                STORE_OUT(2304 + g * 5 + o, r);
            }
        }
        __syncthreads();
    }

    for (int k = 0; k < 2; k++) {
        {
            int i0 = w * 16;
            float p = 0.f;
            for (int i = i0; i < i0 + 16; i++)
                p += zf[i] * ldw(fW1, (size_t)k * 4096 + (size_t)i * 64 + lane, f32);
            part[w][lane] = p;
        }
        __syncthreads();
        if (w == 0) {
            float a = part[0][lane] + part[1][lane] + part[2][lane] + part[3][lane]
                    + ldw(fb1, k * 64 + lane, f32);
            tmp[lane] = fmaxf(a, 0.f);
        }
        __syncthreads();
        if (w == 0) {
            float v = tmp[lane] * ldw(fW2, k * 64 + lane, f32);
#pragma unroll
            for (int mask = 1; mask <= 32; mask <<= 1) v += __shfl_xor(v, mask);
            if (lane == 0) {
                float r = v + ldw(fb2, k, f32);
                bin[91 + k] = r;
                STORE_OUT(3584 + k * 256 + g, r);
            }
        }
        __syncthreads();
    }

    {
        int i0 = w * 24, i1 = min(93, i0 + 24);
        float p = 0.f;
        for (int i = i0; i < i1; i++) p += bin[i] * ldw(bW1, (size_t)i * 64 + lane, f32);
        part[w][lane] = p;
    }
    __syncthreads();
    if (w == 0) {
        float a = part[0][lane] + part[1][lane] + part[2][lane] + part[3][lane]
                + ldw(bb1, lane, f32);
        tmp[lane] = fmaxf(a, 0.f);
    }
    __syncthreads();
    if (w == 0) {
        float v = tmp[lane] * ldw(bW2, lane, f32);
#pragma unroll
        for (int mask = 1; mask <= 32; mask <<= 1) v += __shfl_xor(v, mask);
        if (lane == 0) {
            float r = v + ldw(bb2, 0, f32);
            bin[93] = r;
            STORE_OUT(4096 + g, r);
        }
    }
    __syncthreads();

    {
        int i0 = w * 24, i1 = min(94, i0 + 24);
        float p = 0.f;
        for (int i = i0; i < i1; i++) p += bin[i] * ldw(zW1, (size_t)i * 64 + lane, f32);
        part[w][lane] = p;
    }
    __syncthreads();
    if (w == 0) {
        float a = part[0][lane] + part[1][lane] + part[2][lane] + part[3][lane]
                + ldw(zb1, lane, f32);
        tmp[lane] = fmaxf(a, 0.f);
    }
    __syncthreads();
    for (int base = 0; base < 8; base += 4) {
        int o = base + w;
        float v = tmp[lane] * ldw(zW2, (size_t)lane * 8 + o, f32);
#pragma unroll
        for (int mask = 1; mask <= 32; mask <<= 1) v += __shfl_xor(v, mask);
        if (lane == 0) STORE_OUT(4352 + g * 8 + o, v + ldw(zb2, o, f32));
    }
#undef STORE_OUT
}

// ---------------- host ----------------

extern "C" void kernel_launch(void* const* d_in, const int* in_sizes, int n_in,
                              void* d_out, int out_size, void* d_ws, size_t ws_size,
                              hipStream_t stream) {
    const void* x     = d_in[0];
    const int*  ei    = (const int*)d_in[1];
    const int*  batch = (const int*)d_in[2];

    int N = in_sizes[0] / 128;
    int E = in_sizes[1] / 2;

    char* w = (char*)d_ws;
    float4* asad = (float4*)w;              w += (size_t)N * 16;
    unsigned short* A = (unsigned short*)w; w += (size_t)N * 128 * 2;
    unsigned short* B = (unsigned short*)w; w += (size_t)N * 128 * 2;
    float2* pE = (float2*)w;                w += (size_t)E * 8;
    unsigned short* Wt = (unsigned short*)w; w += 3 * 16384 * 2;
    float* asF = (float*)w;                 w += 384 * 4;
    float* adF = (float*)w;                 w += 384 * 4;
    float* bF = (float*)w;                  w += 384 * 4;
    int* counts = (int*)w;                  w += (size_t)N * 4;
    int* offs = (int*)w;                    w += (size_t)N * 4;
    int* rank = (int*)w;                    w += (size_t)E * 4;
    int* adj = (int*)w;                     w += (size_t)E * 4;
    int* bsums = (int*)w;                   w += 512 * 4;
    int* node0 = (int*)w;                   w += 256 * 4;
    int* flag = (int*)w;                    w += 64;

    int nb = (N + 255) / 256;
    int nbx = (N * 128 + 255) / 256;

    hipMemsetAsync(flag, 0, 64, stream);
    hipMemsetAsync(counts, 0, (size_t)N * 4, stream);

    k_detect<<<16, 256, 0, stream>>>(x, flag);

    k_prep_fused<<<nbx + 194 + nb, 256, 0, stream>>>(
        x, A, N * 128, d_in[3], Wt, d_in[4], d_in[5], d_in[6],
        asF, adF, bF, batch, node0, N, flag, nbx, nb);

    k_hist<<<(E + 255) / 256, 256, 0, stream>>>(ei, counts, rank, E);
    k_scan1<<<nb, 256, 0, stream>>>(counts, offs, bsums, N);
    k_scan2<<<1, 512, 0, stream>>>(bsums, nb);
    k_scan3<<<nb, 256, 0, stream>>>(offs, bsums, N);
    k_scatter<<<(E + 255) / 256, 256, 0, stream>>>(ei, offs, rank, adj, E);

    // agg grid: 2 nodes per wave, 4 waves per block
    int nwaves = (N + 1) / 2;
    int aggblocks = (nwaves + 3) / 4;
    for (int l = 0; l < 3; l++) {
        k_gemm_mfma<<<(N + 63) / 64, 256, 0, stream>>>(
            A, Wt + (size_t)l * 16384, B, asad, asF + l * 128, adF + l * 128, N);
        k_gat_agg<<<aggblocks, 256, 0, stream>>>(
            (const uint4*)B, asad, offs, counts, adj,
            bF + l * 128, (uint4*)A, pE, N, (l < 2) ? 1 : 0);
    }

    k_heads<<<256, 256, 0, stream>>>(A, x, node0,
                                     d_in[7], d_in[8], d_in[9], d_in[10], d_in[11], d_in[12],
                                     d_in[13], d_in[14], d_in[15], d_in[16],
                                     d_in[17], d_in[18], d_in[19], d_in[20],
                                     d_in[21], d_in[22], d_in[23], d_in[24],
                                     d_in[25], d_in[26], d_in[27], d_in[28],
                                     d_out, flag);
}

// Round 13
// 581.182 us; speedup vs baseline: 1.0316x; 1.0012x over previous
//
#include <hip/hip_runtime.h>
#include <hip/hip_bf16.h>

typedef __hip_bfloat16 bf16;
typedef __attribute__((ext_vector_type(8))) short short8;
typedef __attribute__((ext_vector_type(4))) float floatx4;

__device__ __forceinline__ float b2f(bf16 v) { return __bfloat162float(v); }
__device__ __forceinline__ float us2f(unsigned short u) {
    return __uint_as_float(((unsigned)u) << 16);
}
__device__ __forceinline__ unsigned short f2us(float f) {
    bf16 h = __float2bfloat16(f);
    return *(unsigned short*)&h;
}
__device__ __forceinline__ float lo2f(unsigned hv) { return __uint_as_float(hv << 16); }
__device__ __forceinline__ float hi2f(unsigned hv) { return __uint_as_float(hv & 0xffff0000u); }
__device__ __forceinline__ float leaky(float v) { return v > 0.f ? v : 0.2f * v; }

// flag-aware raw-input read by ELEMENT index: flag==1 -> f32 storage, else bf16
__device__ __forceinline__ float ldw(const void* p, size_t i, int f32) {
    return f32 ? ((const float*)p)[i] : b2f(((const bf16*)p)[i]);
}

// ---------------- dtype detection ----------------
__global__ void k_detect(const void* x, int* flag) {
    int i = blockIdx.x * blockDim.x + threadIdx.x;
    float v = b2f(((const bf16*)x)[i]);
    if (!(fabsf(v) < 1e10f)) atomicOr(flag, 1);  // NaN/inf/huge -> f32 storage
}

// ---------------- fused prep: x->bf16, W transpose->bf16, small weights, node0 ----
__global__ void k_prep_fused(const void* __restrict__ x, unsigned short* __restrict__ Ab,
                             int nx128,
                             const void* __restrict__ gw, unsigned short* __restrict__ Wt,
                             const void* as_, const void* ad_, const void* b_,
                             float* asF, float* adF, float* bF,
                             const int* __restrict__ batch, int* __restrict__ node0, int N,
                             const int* __restrict__ flag, int nbx, int nbN) {
    int b = blockIdx.x;
    int t = threadIdx.x;
    int f32 = *flag;
    if (b < nbx) {
        int i = b * 256 + t;
        if (i < nx128) Ab[i] = f2us(ldw(x, i, f32));
    } else if (b < nbx + 192) {
        int i = (b - nbx) * 256 + t;  // exactly 3*16384
        int l = i >> 14, rem = i & 16383, n = rem >> 7, k = rem & 127;
        Wt[i] = f2us(ldw(gw, (size_t)l * 16384 + (size_t)k * 128 + n, f32));
    } else if (b < nbx + 194) {
        int i = (b - nbx - 192) * 256 + t;
        if (i < 384) {
            asF[i] = ldw(as_, i, f32);
            adF[i] = ldw(ad_, i, f32);
            bF[i] = ldw(b_, i, f32);
        }
    } else {
        int i = (b - nbx - 194) * 256 + t;
        if (i < N) {
            int bb = batch[i];
            if (i == 0 || batch[i - 1] != bb) node0[bb] = i;
        }
    }
}

// ---------------- graph build ----------------
__global__ void k_hist(const int* __restrict__ ei, int* __restrict__ counts,
                       int* __restrict__ rank, int E) {
    int e = blockIdx.x * blockDim.x + threadIdx.x;
    if (e < E) rank[e] = atomicAdd(&counts[ei[E + e]], 1);
}

__global__ void k_scan1(const int* __restrict__ counts, int* __restrict__ offs,
                        int* __restrict__ bsums, int n) {
    __shared__ int s[256];
    int tid = threadIdx.x;
    int i = blockIdx.x * 256 + tid;
    int v = (i < n) ? counts[i] : 0;
    s[tid] = v;
    __syncthreads();
    for (int d = 1; d < 256; d <<= 1) {
        int t = (tid >= d) ? s[tid - d] : 0;
        __syncthreads();
        s[tid] += t;
        __syncthreads();
    }
    int incl = s[tid];
    if (i < n) offs[i] = incl - v;
    if (tid == 255) bsums[blockIdx.x] = incl;
}

__global__ void k_scan2(int* __restrict__ bsums, int nb) {
    __shared__ int s[512];
    int tid = threadIdx.x;
    int v = (tid < nb) ? bsums[tid] : 0;
    s[tid] = v;
    __syncthreads();
    for (int d = 1; d < 512; d <<= 1) {
        int t = (tid >= d) ? s[tid - d] : 0;
        __syncthreads();
        s[tid] += t;
        __syncthreads();
    }
    bsums[tid] = s[tid] - v;
}

__global__ void k_scan3(int* __restrict__ offs, const int* __restrict__ bsums, int n) {
    int i = blockIdx.x * 256 + threadIdx.x;
    if (i < n) offs[i] += bsums[blockIdx.x];
}

// XCD-partitioned scatter: 8 blocks (one per XCD via blockIdx&7) per edge
// chunk; each writes only edges whose dst falls in its contiguous node range,
// so every adj cache line is dirtied by ONE XCD's L2 and flushed whole once
// (kills the 17x cross-XCD partial-line write amplification seen in R6).
// blockIdx->XCD mapping is a speed heuristic only; correctness is unaffected.
__global__ void k_scatter8(const int* __restrict__ ei, const int* __restrict__ offs,
                           const int* __restrict__ rank, int* __restrict__ adj,
                           int E, int N) {
    int xcd = blockIdx.x & 7;
    int e = (blockIdx.x >> 3) * 256 + threadIdx.x;
    if (e >= E) return;
    int d = ei[E + e];
    int lo = (int)(((long long)N * xcd) >> 3);
    int hi = (int)(((long long)N * (xcd + 1)) >> 3);
    if (d >= lo && d < hi) adj[offs[d] + rank[e]] = ei[e];
}

// ---------------- MFMA GEMM + fused attention scalars ----------------
// A-fragments load DIRECTLY from global (16 B/lane, coalesced) — LDS used only
// for the C-transpose epilogue buffer.
__global__ __launch_bounds__(256) void k_gemm_mfma(
    const unsigned short* __restrict__ Ab, const unsigned short* __restrict__ Wt,
    unsigned short* __restrict__ Bb, float4* __restrict__ asadv,
    const float* __restrict__ asF, const float* __restrict__ adF, int N) {
    __shared__ unsigned short Cs[64 * 136];

    int t = threadIdx.x;
    int r0 = blockIdx.x * 64;

    int lane = t & 63;
    int w = t >> 6;
    int ln = lane & 15;
    int quad = lane >> 4;

    int arow = r0 + w * 16 + ln;
    if (arow >= N) arow = N - 1;  // clamp (stores are guarded)
    const unsigned short* ap = Ab + (size_t)arow * 128 + quad * 8;

    short8 afrag[4];
#pragma unroll
    for (int kt = 0; kt < 4; kt++)
        afrag[kt] = *(const short8*)(ap + kt * 32);

    floatx4 acc[8];
#pragma unroll
    for (int nt = 0; nt < 8; nt++) acc[nt] = (floatx4){0.f, 0.f, 0.f, 0.f};

#pragma unroll
    for (int nt = 0; nt < 8; nt++) {
        const unsigned short* wp = Wt + (size_t)(nt * 16 + ln) * 128 + quad * 8;
#pragma unroll
        for (int kt = 0; kt < 4; kt++) {
            short8 bfrag = *(const short8*)(wp + kt * 32);
            acc[nt] = __builtin_amdgcn_mfma_f32_16x16x32_bf16(afrag[kt], bfrag, acc[nt], 0, 0, 0);
        }
    }

    float as0[4] = {0, 0, 0, 0}, as1[4] = {0, 0, 0, 0};
    float ad0[4] = {0, 0, 0, 0}, ad1[4] = {0, 0, 0, 0};
#pragma unroll
    for (int nt = 0; nt < 8; nt++) {
        float asc = asF[nt * 16 + ln];
        float adc = adF[nt * 16 + ln];
#pragma unroll
        for (int r = 0; r < 4; r++) {
            float v = acc[nt][r];
            Cs[(w * 16 + quad * 4 + r) * 136 + nt * 16 + ln] = f2us(v);
            if (nt < 4) { as0[r] += v * asc; ad0[r] += v * adc; }
            else        { as1[r] += v * asc; ad1[r] += v * adc; }
        }
    }
#pragma unroll
    for (int mask = 1; mask <= 8; mask <<= 1) {
#pragma unroll
        for (int r = 0; r < 4; r++) {
            as0[r] += __shfl_xor(as0[r], mask);
            as1[r] += __shfl_xor(as1[r], mask);
            ad0[r] += __shfl_xor(ad0[r], mask);
            ad1[r] += __shfl_xor(ad1[r], mask);
        }
    }
    if (ln == 0) {
#pragma unroll
        for (int r = 0; r < 4; r++) {
            int row = r0 + w * 16 + quad * 4 + r;
            if (row < N) asadv[row] = make_float4(as0[r], as1[r], ad0[r], ad1[r]);
        }
    }
    __syncthreads();

    {
        int row = t >> 2;
        int cseg = (t & 3) * 32;
        if (r0 + row < N) {
            const short8* srcp = (const short8*)&Cs[row * 136 + cseg];
            short8* dstp = (short8*)&Bb[(size_t)(r0 + row) * 128 + cseg];
#pragma unroll
            for (int u = 0; u < 4; u++) dstp[u] = srcp[u];
        }
    }
}

// ---------------- GAT aggregation: TWO nodes per wave, depth-4 pipeline ----------------
// (R9 configuration — best measured: 60.1 µs. uint2 loads, 4 rows prefetched
// per node, both heads' alphas shfl'd and selected by the CONSUMER lane.)
__global__ void k_gat_agg(const uint2* __restrict__ Bu2, const float4* __restrict__ asadv,
                          const int* __restrict__ offs, const int* __restrict__ counts,
                          const int* __restrict__ adj, const float* __restrict__ biasF,
                          uint2* __restrict__ Au2, float2* __restrict__ pE,
                          int n, int dorelu) {
    int wave = (blockIdx.x * blockDim.x + threadIdx.x) >> 6;
    int lane = threadIdx.x & 63;
    int hl = lane & 31;          // lane within node-half
    int hb = lane & 32;          // shfl broadcast base for this half
    int node = wave * 2 + (lane >> 5);
    if (node >= n) return;
    int head = hl >> 4;          // channels 4hl..4hl+3

    float4 self = asadv[node];
    float ad0 = self.z, ad1 = self.w;
    float es0 = __expf(leaky(self.x + ad0));
    float es1 = __expf(leaky(self.y + ad1));

    int o = offs[node], c = counts[node];
    uint2 hvs = Bu2[(size_t)node * 32 + hl];
    float acc0, acc1, acc2, acc3;

    if (c <= 32) {
        // ---- fast path ----
        int src_r = 0;
        float p0 = 0.f, p1 = 0.f;
        if (hl < c) {
            src_r = adj[o + hl];
            float4 av = asadv[src_r];
            p0 = __expf(leaky(av.x + ad0));
            p1 = __expf(leaky(av.y + ad1));
        }
        float t0 = p0, t1 = p1;
#pragma unroll
        for (int mask = 1; mask <= 16; mask <<= 1) {
            t0 += __shfl_xor(t0, mask);
            t1 += __shfl_xor(t1, mask);
        }
        float inv0 = 1.f / (es0 + t0 + 1e-16f);
        float inv1 = 1.f / (es1 + t1 + 1e-16f);
        p0 *= inv0;                       // pre-scaled alphas
        p1 *= inv1;
        float aself = head ? es1 * inv1 : es0 * inv0;
        acc0 = aself * lo2f(hvs.x);
        acc1 = aself * hi2f(hvs.x);
        acc2 = aself * lo2f(hvs.y);
        acc3 = aself * hi2f(hvs.y);

        // prologue: prefetch rows for edges 0..3
        uint2 hq[4];
#pragma unroll
        for (int j = 0; j < 4; j++) {
            int s2 = __shfl(src_r, hb + j);
            hq[j] = make_uint2(0u, 0u);
            if (j < c) hq[j] = Bu2[(size_t)s2 * 32 + hl];
        }

        for (int base = 0; base < c; base += 4) {
            uint2 cur[4];
            float av4[4];
#pragma unroll
            for (int j = 0; j < 4; j++) {
                cur[j] = hq[j];
                int idx = (base + j) & 31;
                float a0 = __shfl(p0, hb + idx);   // both heads broadcast;
                float a1 = __shfl(p1, hb + idx);   // consumer selects its head
                float a = head ? a1 : a0;
                av4[j] = (base + j < c) ? a : 0.f; // tail guard (stale cur is finite)
            }
            // issue next 4 loads before consuming cur
#pragma unroll
            for (int j = 0; j < 4; j++) {
                int nx = base + 4 + j;
                int s2 = __shfl(src_r, hb + (nx & 31));
                if (nx < c) hq[j] = Bu2[(size_t)s2 * 32 + hl];
            }
#pragma unroll
            for (int j = 0; j < 4; j++) {
                acc0 += av4[j] * lo2f(cur[j].x);
                acc1 += av4[j] * hi2f(cur[j].x);
                acc2 += av4[j] * lo2f(cur[j].y);
                acc3 += av4[j] * hi2f(cur[j].y);
            }
        }
    } else {
        // ---- slow path (rare, c>32): alphas staged in global scratch ----
        float sum0 = es0, sum1 = es1;
        for (int base = 0; base < c; base += 32) {
            int i = base + hl;
            float p0 = 0.f, p1 = 0.f;
            if (i < c) {
                int s = adj[o + i];
                float4 av = asadv[s];
                p0 = __expf(leaky(av.x + ad0));
                p1 = __expf(leaky(av.y + ad1));
                pE[o + i] = make_float2(p0, p1);
            }
            float t0 = p0, t1 = p1;
#pragma unroll
            for (int mask = 1; mask <= 16; mask <<= 1) {
                t0 += __shfl_xor(t0, mask);
                t1 += __shfl_xor(t1, mask);
            }
            sum0 += t0; sum1 += t1;
        }
        float inv0 = 1.f / (sum0 + 1e-16f);
        float inv1 = 1.f / (sum1 + 1e-16f);
        float aself = head ? es1 * inv1 : es0 * inv0;
        float invh = head ? inv1 : inv0;
        acc0 = aself * lo2f(hvs.x);
        acc1 = aself * hi2f(hvs.x);
        acc2 = aself * lo2f(hvs.y);
        acc3 = aself * hi2f(hvs.y);
        for (int i = 0; i < c; i++) {
            int s = adj[o + i];
            float2 pp = pE[o + i];
            uint2 hv = Bu2[(size_t)s * 32 + hl];
            float a = (head ? pp.y : pp.x) * invh;
            acc0 += a * lo2f(hv.x);
            acc1 += a * hi2f(hv.x);
            acc2 += a * lo2f(hv.y);
            acc3 += a * hi2f(hv.y);
        }
    }

    float2 bb = ((const float2*)biasF)[hl];
    float o0 = acc0 + bb.x;
    float o1 = acc1 + bb.y;
    if (dorelu) { o0 = fmaxf(o0, 0.f); o1 = fmaxf(o1, 0.f); }
    float2 bb2v = ((const float2*)biasF)[hl + 32];
    // NOTE: channels for lane hl are 2*hl (x) and 2*hl+1; uint2 covers 4 ch:
    // hvs.x -> ch 4hl..4hl+1? No: Bu2 row = 32 uint2 = 64 dwords? Layout check:
    // row is 128 bf16 = 64 dwords = 32 uint2; lane hl covers dwords 2hl,2hl+1
    // = channels 4hl..4hl+3. Bias must match: float4 at index hl.
    (void)bb; (void)bb2v;
    float4 bb4 = ((const float4*)biasF)[hl];
    float q0 = acc0 + bb4.x;
    float q1 = acc1 + bb4.y;
    float q2 = acc2 + bb4.z;
    float q3 = acc3 + bb4.w;
    if (dorelu) {
        q0 = fmaxf(q0, 0.f); q1 = fmaxf(q1, 0.f);
        q2 = fmaxf(q2, 0.f); q3 = fmaxf(q3, 0.f);
    }
    Au2[(size_t)node * 32 + hl] =
        make_uint2(((unsigned)f2us(q1) << 16) | f2us(q0),
                   ((unsigned)f2us(q3) << 16) | f2us(q2));
}

// ---------------- heads: one block (4 waves) per graph ----------------
__global__ __launch_bounds__(256) void k_heads(
    const unsigned short* __restrict__ Ab, const void* __restrict__ x,
    const int* __restrict__ node0,
    const void* sW, const void* sb,
    const void* pW1, const void* pb1, const void* pW2, const void* pb2,
    const void* cW1, const void* cb1, const void* cW2, const void* cb2,
    const void* fW1, const void* fb1, const void* fW2, const void* fb2,
    const void* bW1, const void* bb1, const void* bW2, const void* bb2,
    const void* zW1, const void* zb1, const void* zW2, const void* zb2,
    void* __restrict__ outv, const int* __restrict__ flag) {
    int g = blockIdx.x;
    int t = threadIdx.x;
    int w = t >> 6;
    int lane = t & 63;
    int f32 = *flag;
    bf16* outb = (bf16*)outv;
    float* outf = (float*)outv;
    __shared__ float in150[152];
    __shared__ float part[4][64];
    __shared__ float zf[64];
    __shared__ float tmp[64];
    __shared__ float bin[96];

#define STORE_OUT(idx, val) do { if (f32) outf[idx] = (val); else outb[idx] = __float2bfloat16(val); } while (0)

    int n0 = node0[g];
    if (t < 128) in150[t] = us2f(Ab[(size_t)n0 * 128 + t]);
    else if (t < 150) in150[t] = ldw(x, (size_t)n0 * 128 + (t - 128), f32);
    __syncthreads();
    if (t >= 64 && t < 86) bin[t] = in150[128 + (t - 64)];

    {
        int i0 = w * 38, i1 = min(150, i0 + 38);
        float p = 0.f;
        for (int i = i0; i < i1; i++) p += in150[i] * ldw(sW, (size_t)i * 64 + lane, f32);
        part[w][lane] = p;
    }
    __syncthreads();
    if (w == 0) {
        float a = part[0][lane] + part[1][lane] + part[2][lane] + part[3][lane]
                + ldw(sb, lane, f32);
        a = fmaxf(a, 0.f);
        zf[lane] = a;
        bin[lane] = a;
    }
    __syncthreads();

    for (int k = 0; k < 3; k++) {
        {
            int i0 = w * 16;
            float p = 0.f;
            for (int i = i0; i < i0 + 16; i++)
                p += zf[i] * ldw(pW1, (size_t)k * 4096 + (size_t)i * 64 + lane, f32);
            part[w][lane] = p;
        }
        __syncthreads();
        if (w == 0) {
            float a = part[0][lane] + part[1][lane] + part[2][lane] + part[3][lane]
                    + ldw(pb1, k * 64 + lane, f32);
            tmp[lane] = fmaxf(a, 0.f);
        }
        __syncthreads();
        if (w < 3) {
            float v = tmp[lane] * ldw(pW2, (size_t)k * 192 + (size_t)lane * 3 + w, f32);
#pragma unroll
            for (int mask = 1; mask <= 32; mask <<= 1) v += __shfl_xor(v, mask);
            if (lane == 0) STORE_OUT(k * 768 + g * 3 + w, v + ldw(pb2, k * 3 + w, f32));
        }
        __syncthreads();
    }

    {
        int i0 = w * 16;
        float p = 0.f;
        for (int i = i0; i < i0 + 16; i++)
            p += zf[i] * ldw(cW1, (size_t)i * 64 + lane, f32);
        part[w][lane] = p;
    }
    __syncthreads();
    if (w == 0) {
        float a = part[0][lane] + part[1][lane] + part[2][lane] + part[3][lane]
                + ldw(cb1, lane, f32);
        tmp[lane] = fmaxf(a, 0.f);
    }
    __syncthreads();
    for (int base = 0; base < 5; base += 4) {
        int o = base + w;
        if (o < 5) {
            float v = tmp[lane] * ldw(cW2, (size_t)lane * 5 + o, f32);
#pragma unroll
            for (int mask = 1; mask <= 32; mask <<= 1) v += __shfl_xor(v, mask);
            if (lane == 0) {
                float r = v + ldw(cb2, o, f32);
                bin[86 + o] = r;
                STORE_OUT(2304 + g * 5 + o, r);
            }
        }
        __syncthreads();
    }

    for (int k = 0; k < 2; k++) {
        {
            int i0 = w * 16;
            float p = 0.f;
            for (int i = i0; i < i0 + 16; i++)
                p += zf[i] * ldw(fW1, (size_t)k * 4096 + (size_t)i * 64 + lane, f32);
            part[w][lane] = p;
        }
        __syncthreads();
        if (w == 0) {
            float a = part[0][lane] + part[1][lane] + part[2][lane] + part[3][lane]
                    + ldw(fb1, k * 64 + lane, f32);
            tmp[lane] = fmaxf(a, 0.f);
        }
        __syncthreads();
        if (w == 0) {
            float v = tmp[lane] * ldw(fW2, k * 64 + lane, f32);
#pragma unroll
            for (int mask = 1; mask <= 32; mask <<= 1) v += __shfl_xor(v, mask);
            if (lane == 0) {
                float r = v + ldw(fb2, k, f32);
                bin[91 + k] = r;
                STORE_OUT(3584 + k * 256 + g, r);
            }
        }
        __syncthreads();
    }

    {
        int i0 = w * 24, i1 = min(93, i0 + 24);
        float p = 0.f;
        for (int i = i0; i < i1; i++) p += bin[i] * ldw(bW1, (size_t)i * 64 + lane, f32);
        part[w][lane] = p;
    }
    __syncthreads();
    if (w == 0) {
        float a = part[0][lane] + part[1][lane] + part[2][lane] + part[3][lane]
                + ldw(bb1, lane, f32);
        tmp[lane] = fmaxf(a, 0.f);
    }
    __syncthreads();
    if (w == 0) {
        float v = tmp[lane] * ldw(bW2, lane, f32);
#pragma unroll
        for (int mask = 1; mask <= 32; mask <<= 1) v += __shfl_xor(v, mask);
        if (lane == 0) {
            float r = v + ldw(bb2, 0, f32);
            bin[93] = r;
            STORE_OUT(4096 + g, r);
        }
    }
    __syncthreads();

    {
        int i0 = w * 24, i1 = min(94, i0 + 24);
        float p = 0.f;
        for (int i = i0; i < i1; i++) p += bin[i] * ldw(zW1, (size_t)i * 64 + lane, f32);
        part[w][lane] = p;
    }
    __syncthreads();
    if (w == 0) {
        float a = part[0][lane] + part[1][lane] + part[2][lane] + part[3][lane]
                + ldw(zb1, lane, f32);
        tmp[lane] = fmaxf(a, 0.f);
    }
    __syncthreads();
    for (int base = 0; base < 8; base += 4) {
        int o = base + w;
        float v = tmp[lane] * ldw(zW2, (size_t)lane * 8 + o, f32);
#pragma unroll
        for (int mask = 1; mask <= 32; mask <<= 1) v += __shfl_xor(v, mask);
        if (lane == 0) STORE_OUT(4352 + g * 8 + o, v + ldw(zb2, o, f32));
    }
#undef STORE_OUT
}

// ---------------- host ----------------

extern "C" void kernel_launch(void* const* d_in, const int* in_sizes, int n_in,
                              void* d_out, int out_size, void* d_ws, size_t ws_size,
                              hipStream_t stream) {
    const void* x     = d_in[0];
    const int*  ei    = (const int*)d_in[1];
    const int*  batch = (const int*)d_in[2];

    int N = in_sizes[0] / 128;
    int E = in_sizes[1] / 2;

    char* w = (char*)d_ws;
    float4* asad = (float4*)w;              w += (size_t)N * 16;
    unsigned short* A = (unsigned short*)w; w += (size_t)N * 128 * 2;
    unsigned short* B = (unsigned short*)w; w += (size_t)N * 128 * 2;
    float2* pE = (float2*)w;                w += (size_t)E * 8;
    unsigned short* Wt = (unsigned short*)w; w += 3 * 16384 * 2;
    float* asF = (float*)w;                 w += 384 * 4;
    float* adF = (float*)w;                 w += 384 * 4;
    float* bF = (float*)w;                  w += 384 * 4;
    int* counts = (int*)w;                  w += (size_t)N * 4;
    int* offs = (int*)w;                    w += (size_t)N * 4;
    int* rank = (int*)w;                    w += (size_t)E * 4;
    int* adj = (int*)w;                     w += (size_t)E * 4;
    int* bsums = (int*)w;                   w += 512 * 4;
    int* node0 = (int*)w;                   w += 256 * 4;
    int* flag = (int*)w;                    w += 64;

    int nb = (N + 255) / 256;
    int nbx = (N * 128 + 255) / 256;

    hipMemsetAsync(flag, 0, 64, stream);
    hipMemsetAsync(counts, 0, (size_t)N * 4, stream);

    k_detect<<<16, 256, 0, stream>>>(x, flag);

    k_prep_fused<<<nbx + 194 + nb, 256, 0, stream>>>(
        x, A, N * 128, d_in[3], Wt, d_in[4], d_in[5], d_in[6],
        asF, adF, bF, batch, node0, N, flag, nbx, nb);

    k_hist<<<(E + 255) / 256, 256, 0, stream>>>(ei, counts, rank, E);
    k_scan1<<<nb, 256, 0, stream>>>(counts, offs, bsums, N);
    k_scan2<<<1, 512, 0, stream>>>(bsums, nb);
    k_scan3<<<nb, 256, 0, stream>>>(offs, bsums, N);
    k_scatter8<<<8 * ((E + 255) / 256), 256, 0, stream>>>(ei, offs, rank, adj, E, N);

    // agg grid: 2 nodes per wave, 4 waves per block
    int nwaves = (N + 1) / 2;
    int aggblocks = (nwaves + 3) / 4;
    for (int l = 0; l < 3; l++) {
        k_gemm_mfma<<<(N + 63) / 64, 256, 0, stream>>>(
            A, Wt + (size_t)l * 16384, B, asad, asF + l * 128, adF + l * 128, N);
        k_gat_agg<<<aggblocks, 256, 0, stream>>>(
            (const uint2*)B, asad, offs, counts, adj,
            bF + l * 128, (uint2*)A, pE, N, (l < 2) ? 1 : 0);
    }

    k_heads<<<256, 256, 0, stream>>>(A, x, node0,
                                     d_in[7], d_in[8], d_in[9], d_in[10], d_in[11], d_in[12],
                                     d_in[13], d_in[14], d_in[15], d_in[16],
                                     d_in[17], d_in[18], d_in[19], d_in[20],
                                     d_in[21], d_in[22], d_in[23], d_in[24],
                                     d_in[25], d_in[26], d_in[27], d_in[28],
                                     d_out, flag);
}